// Round 4
// baseline (6506.893 us; speedup 1.0000x reference)
//
#include <hip/hip_runtime.h>
#include <hip/hip_bf16.h>
#include <cstdint>
#include <cstddef>

// MMDecoderDoubleBranch R4: ROW-SPLIT waves — zero cross-wave data flow.
// Block = 256 thr (4 waves), 64 rows; each wave owns 16 rows (one MFMA M-tile)
// end-to-end: LSTM, GN (in-wave butterfly), both mode-head GEMMs, out-proj,
// xin feedback. LDS = per-wave-private h/t1/rel slices only. All 4 waves load
// IDENTICAL weight addresses in lockstep (barriers align them) -> L1/L2
// broadcast. R3's cross-wave channel split failed replay validation; this
// structure has no inter-wave dependencies to race.

#define HD 128
#define TT 30
#define MM 6
#define B_ROWS 32768

typedef _Float16 f16x8 __attribute__((ext_vector_type(8)));
typedef float f32x4 __attribute__((ext_vector_type(4)));

__device__ __forceinline__ float fast_rcp(float x) { return __builtin_amdgcn_rcpf(x); }
__device__ __forceinline__ float sigm(float x) { return fast_rcp(1.f + __expf(-x)); }
__device__ __forceinline__ float tanhf_(float x) { return 1.f - 2.f * fast_rcp(__expf(2.f * x) + 1.f); }
__device__ __forceinline__ float selu_(float x) {
  const float sc = 1.0507009873554805f;
  const float al = 1.6732632423543772f;
  return x > 0.f ? sc * x : sc * al * (__expf(x) - 1.f);
}

__device__ __forceinline__ f32x4 shx4(f32x4 v, int m) {
  f32x4 r;
  r[0] = __shfl_xor(v[0], m, 64);
  r[1] = __shfl_xor(v[1], m, 64);
  r[2] = __shfl_xor(v[2], m, 64);
  r[3] = __shfl_xor(v[3], m, 64);
  return r;
}

// ---- weight prep: fragment-ordered f16 (same layouts as R2/R3) ----
// Wg:   [t16=g*8+cg][ch=0..4][lane][8]   (32 tiles * 2560)
// W1p/W2p: per mode [ct][ch=0..3][lane][8]; cW1p/cW2p: [ct][ch][lane][8]
__global__ __launch_bounds__(256) void prep_weights(
    const float* __restrict__ W_ih, const float* __restrict__ W_hh,
    const float* __restrict__ b_ih, const float* __restrict__ b_hh,
    const float* __restrict__ mW1, const float* __restrict__ mW2,
    const float* __restrict__ cW1, const float* __restrict__ cW2,
    _Float16* __restrict__ Wg, _Float16* __restrict__ W1p, _Float16* __restrict__ W2p,
    _Float16* __restrict__ cW1p, _Float16* __restrict__ cW2p, float* __restrict__ bg) {
  int n = blockIdx.x * 256 + threadIdx.x;
  if (n < 81920) {
    int t16 = n / 2560, r = n % 2560;
    int ch = r / 512, l = (r >> 3) & 63, j = r & 7;
    int q = l >> 4, cl = l & 15;
    int row = (t16 >> 3) * 128 + (t16 & 7) * 16 + cl;
    int k = ch * 32 + q * 8 + j;
    float v = 0.f;
    if (k < 128) v = W_hh[row * 128 + k];
    else if (k < 144) v = W_ih[row * 16 + (k - 128)];
    Wg[n] = (_Float16)v;
    return;
  }
  n -= 81920;
  if (n < 98304) {
    int m = n >> 14, r = n & 16383;
    int ct = r >> 11, ch = (r >> 9) & 3, l = (r >> 3) & 63, j = r & 7;
    int q = l >> 4, cl = l & 15;
    int outcol = ct * 16 + cl, k = ch * 32 + q * 8 + j;
    W1p[n] = (_Float16)mW1[(m * 128 + k) * 128 + outcol];
    return;
  }
  n -= 98304;
  if (n < 98304) {
    int m = n >> 14, r = n & 16383;
    int ct = r >> 11, ch = (r >> 9) & 3, l = (r >> 3) & 63, j = r & 7;
    int q = l >> 4, cl = l & 15;
    int outcol = ct * 16 + cl, k = ch * 32 + q * 8 + j;
    W2p[n] = (_Float16)mW2[(m * 128 + k) * 128 + outcol];
    return;
  }
  n -= 98304;
  if (n < 16384) {
    int ct = n >> 11, ch = (n >> 9) & 3, l = (n >> 3) & 63, j = n & 7;
    int q = l >> 4, cl = l & 15;
    int outcol = ct * 16 + cl, k = ch * 32 + q * 8 + j;
    cW1p[n] = (_Float16)cW1[k * 128 + outcol];
    return;
  }
  n -= 16384;
  if (n < 16384) {
    int ct = n >> 11, ch = (n >> 9) & 3, l = (n >> 3) & 63, j = n & 7;
    int q = l >> 4, cl = l & 15;
    int outcol = ct * 16 + cl, k = ch * 32 + q * 8 + j;
    cW2p[n] = (_Float16)cW2[k * 128 + outcol];
    return;
  }
  n -= 16384;
  if (n < 512) bg[n] = b_ih[n] + b_hh[n];
}

// ---- main decoder: 4 waves/block, 16 rows per wave, fully wave-local ----
__global__ __launch_bounds__(256, 2) void mmdec_main(
    const float* __restrict__ last_obs_rel, const float* __restrict__ h0, const float* __restrict__ c0,
    const float* __restrict__ W_se, const float* __restrict__ b_se,
    const float* __restrict__ mg1w, const float* __restrict__ mg1b,
    const float* __restrict__ mg2w, const float* __restrict__ mg2b,
    const float* __restrict__ mWo, const float* __restrict__ mbo,
    const float* __restrict__ cg1w, const float* __restrict__ cg1b,
    const float* __restrict__ cg2w, const float* __restrict__ cg2b,
    const float* __restrict__ cWo, const float* __restrict__ cbo,
    const _Float16* __restrict__ Wg, const _Float16* __restrict__ W1p, const _Float16* __restrict__ W2p,
    const _Float16* __restrict__ cW1p, const _Float16* __restrict__ cW2p, const float* __restrict__ bgp,
    float* __restrict__ out) {
  // per-wave-private slices. h rows: [128 h | 16 x | 16 zeros] f16.
  // strides 336/272 B: 16-B aligned, non-pow2 (breaks LDS bank aliasing).
  __shared__ __align__(16) unsigned char h_smem[4 * 16 * 336];
  __shared__ __align__(16) unsigned char t1_smem[4 * 16 * 272];
  __shared__ float rel_smem[4][16][12];

  const int tid = threadIdx.x;
  const int w = tid >> 6;       // wave id: owns rows [16w, 16w+16) of the block
  const int lane = tid & 63;
  const int q = lane >> 4, cl = lane & 15;
  const int rowbase = blockIdx.x * 64 + w * 16;  // wave's first global row

  auto hrow = [&](int r) -> _Float16* { return (_Float16*)(h_smem + (w * 16 + r) * 336); };
  auto t1row = [&](int r) -> _Float16* { return (_Float16*)(t1_smem + (w * 16 + r) * 272); };

  // ---- init: h0 -> LDS f16 (lane: row cl, col chunk q*32) ----
  {
    const float* src = h0 + (size_t)(rowbase + cl) * HD + q * 32;
    _Float16* dst = hrow(cl) + q * 32;
#pragma unroll
    for (int i = 0; i < 32; i += 8) {
      f16x8 v;
#pragma unroll
      for (int k = 0; k < 8; ++k) v[k] = (_Float16)src[i + k];
      *(f16x8*)(dst + i) = v;
    }
  }
  // ---- init: x = selu(tile(last_obs_rel,6) @ W_se.T + b_se); zero pad ----
  {
    const float r0 = last_obs_rel[(size_t)(rowbase + cl) * 2 + 0];
    const float r1 = last_obs_rel[(size_t)(rowbase + cl) * 2 + 1];
#pragma unroll
    for (int i = 0; i < 4; ++i) {
      const int e = q * 4 + i;
      float acc = b_se[e];
#pragma unroll
      for (int j = 0; j < 12; ++j) acc += ((j & 1) ? r1 : r0) * W_se[e * 12 + j];
      hrow(cl)[128 + e] = (_Float16)selu_(acc);
    }
    if (q < 2) {
      f16x8 z;
#pragma unroll
      for (int i = 0; i < 8; ++i) z[i] = (_Float16)0.f;
      *(f16x8*)(hrow(cl) + 144 + q * 8) = z;
    }
  }
  // ---- init: c0 in C-layout regs (row = q*4+r, col = cg*16+cl) ----
  f32x4 cacc[8];
#pragma unroll
  for (int cg = 0; cg < 8; ++cg)
#pragma unroll
    for (int r = 0; r < 4; ++r)
      cacc[cg][r] = c0[(size_t)(rowbase + q * 4 + r) * HD + cg * 16 + cl];
  // gate biases for this lane's channel columns
  float bgh[8][4];
#pragma unroll
  for (int cg = 0; cg < 8; ++cg)
#pragma unroll
    for (int g = 0; g < 4; ++g) bgh[cg][g] = bgp[g * 128 + cg * 16 + cl];

  f32x4 hC[8];   // h(t) in C-layout (residual source)
  f16x8 ah[4];   // A-frags of h(t), reused by all 6 modes (+conf)
  __syncthreads();

  const size_t confbase = (size_t)B_ROWS * MM * TT * 2;

  for (int t = 0; t < TT; ++t) {
    // ======== LSTM: [h|x|0](K=160) @ Wg^T; update c, h ========
    f16x8 afr[5];
#pragma unroll
    for (int ch = 0; ch < 5; ++ch)
      afr[ch] = *(const f16x8*)(hrow(cl) + ch * 32 + q * 8);

#pragma unroll
    for (int cg = 0; cg < 8; ++cg) {
      f32x4 gacc[4];
#pragma unroll
      for (int g = 0; g < 4; ++g) gacc[g] = f32x4{0.f, 0.f, 0.f, 0.f};
#pragma unroll
      for (int g = 0; g < 4; ++g) {
        const _Float16* bp = Wg + (size_t)(g * 8 + cg) * 2560 + lane * 8;
#pragma unroll
        for (int ch = 0; ch < 5; ++ch) {
          f16x8 b = *(const f16x8*)(bp + ch * 512);
          gacc[g] = __builtin_amdgcn_mfma_f32_16x16x32_f16(afr[ch], b, gacc[g], 0, 0, 0);
        }
      }
      f32x4 hv;
#pragma unroll
      for (int r = 0; r < 4; ++r) {
        const float iv = sigm(gacc[0][r] + bgh[cg][0]);
        const float fv = sigm(gacc[1][r] + bgh[cg][1]);
        const float gv = tanhf_(gacc[2][r] + bgh[cg][2]);
        const float ov = sigm(gacc[3][r] + bgh[cg][3]);
        const float cn = fv * cacc[cg][r] + iv * gv;
        cacc[cg][r] = cn;
        const float hn = ov * tanhf_(cn);
        hv[r] = hn;
        hrow(q * 4 + r)[cg * 16 + cl] = (_Float16)hn;  // C-layout scatter
      }
      hC[cg] = hv;
    }
    __syncthreads();  // h(t) visible (cross-lane within wave) + block lockstep

#pragma unroll
    for (int ch = 0; ch < 4; ++ch)
      ah[ch] = *(const f16x8*)(hrow(cl) + ch * 32 + q * 8);

    // ======== 6 mode heads (fully wave-local) ========
    for (int m = 0; m < MM; ++m) {
      // gemm1: t = h @ mW1[m]
      f32x4 tac[8];
#pragma unroll
      for (int ct = 0; ct < 8; ++ct) {
        const _Float16* bp = W1p + (size_t)m * 16384 + ct * 2048 + lane * 8;
        f32x4 a = {0.f, 0.f, 0.f, 0.f};
#pragma unroll
        for (int ch = 0; ch < 4; ++ch) {
          f16x8 b = *(const f16x8*)(bp + ch * 512);
          a = __builtin_amdgcn_mfma_f32_16x16x32_f16(ah[ch], b, a, 0, 0, 0);
        }
        tac[ct] = a;
      }
      // GN1 stats: full 128-col row-sums via in-wave butterfly over cl
      f32x4 mean, rstd;
      {
        f32x4 s1 = {0.f, 0.f, 0.f, 0.f}, s2 = {0.f, 0.f, 0.f, 0.f};
#pragma unroll
        for (int ct = 0; ct < 8; ++ct) { s1 += tac[ct]; s2 += tac[ct] * tac[ct]; }
#pragma unroll
        for (int sh = 1; sh < 16; sh <<= 1) { s1 += shx4(s1, sh); s2 += shx4(s2, sh); }
        mean = s1 * (1.f / 128.f);
#pragma unroll
        for (int r = 0; r < 4; ++r)
          rstd[r] = rsqrtf(s2[r] * (1.f / 128.f) - mean[r] * mean[r] + 1e-5f);
      }
      __syncthreads();  // WAR guard: prev mode's at1 reads done before t1 overwrite
      // t1 = relu(gn1) -> LDS (C-layout scatter)
#pragma unroll
      for (int ct = 0; ct < 8; ++ct) {
        const float g1 = mg1w[m * HD + ct * 16 + cl];
        const float b1 = mg1b[m * HD + ct * 16 + cl];
#pragma unroll
        for (int r = 0; r < 4; ++r) {
          float v = (tac[ct][r] - mean[r]) * rstd[r] * g1 + b1;
          t1row(q * 4 + r)[ct * 16 + cl] = (_Float16)fmaxf(v, 0.f);
        }
      }
      __syncthreads();  // t1 visible
      // gemm2: t2 = t1 @ mW2[m]
      f16x8 at1[4];
#pragma unroll
      for (int ch = 0; ch < 4; ++ch)
        at1[ch] = *(const f16x8*)(t1row(cl) + ch * 32 + q * 8);
      f32x4 t2a[8];
#pragma unroll
      for (int ct = 0; ct < 8; ++ct) {
        const _Float16* bp = W2p + (size_t)m * 16384 + ct * 2048 + lane * 8;
        f32x4 a = {0.f, 0.f, 0.f, 0.f};
#pragma unroll
        for (int ch = 0; ch < 4; ++ch) {
          f16x8 b = *(const f16x8*)(bp + ch * 512);
          a = __builtin_amdgcn_mfma_f32_16x16x32_f16(at1[ch], b, a, 0, 0, 0);
        }
        t2a[ct] = a;
      }
      // GN2 stats
      {
        f32x4 s1 = {0.f, 0.f, 0.f, 0.f}, s2 = {0.f, 0.f, 0.f, 0.f};
#pragma unroll
        for (int ct = 0; ct < 8; ++ct) { s1 += t2a[ct]; s2 += t2a[ct] * t2a[ct]; }
#pragma unroll
        for (int sh = 1; sh < 16; sh <<= 1) { s1 += shx4(s1, sh); s2 += shx4(s2, sh); }
        mean = s1 * (1.f / 128.f);
#pragma unroll
        for (int r = 0; r < 4; ++r)
          rstd[r] = rsqrtf(s2[r] * (1.f / 128.f) - mean[r] * mean[r] + 1e-5f);
      }
      // t = relu(gn2 + h); out-proj (VALU partials + butterfly over cl)
      f32x4 po0 = {0.f, 0.f, 0.f, 0.f}, po1 = {0.f, 0.f, 0.f, 0.f};
#pragma unroll
      for (int ct = 0; ct < 8; ++ct) {
        const float g2 = mg2w[m * HD + ct * 16 + cl];
        const float b2 = mg2b[m * HD + ct * 16 + cl];
        const float w0 = mWo[((size_t)m * HD + ct * 16 + cl) * 2 + 0];
        const float w1 = mWo[((size_t)m * HD + ct * 16 + cl) * 2 + 1];
#pragma unroll
        for (int r = 0; r < 4; ++r) {
          float v = (t2a[ct][r] - mean[r]) * rstd[r] * g2 + b2 + hC[ct][r];
          v = fmaxf(v, 0.f);
          po0[r] += v * w0;
          po1[r] += v * w1;
        }
      }
#pragma unroll
      for (int sh = 1; sh < 16; sh <<= 1) { po0 += shx4(po0, sh); po1 += shx4(po1, sh); }
      if (cl < 2) {
#pragma unroll
        for (int r = 0; r < 4; ++r) {
          const float val = (cl ? po1[r] : po0[r]) + mbo[m * 2 + cl];
          out[(((size_t)(rowbase + q * 4 + r) * MM + m) * TT + t) * 2 + cl] = val;
          rel_smem[w][q * 4 + r][m * 2 + cl] = val;
        }
      }
    }
    __syncthreads();  // rel visible (cross-lane within wave)

    // ======== xin = selu(rel @ W_se.T + b_se) -> x cols ========
    {
      float rl[12];
#pragma unroll
      for (int j = 0; j < 12; ++j) rl[j] = rel_smem[w][cl][j];
#pragma unroll
      for (int i = 0; i < 4; ++i) {
        const int e = q * 4 + i;
        float acc = b_se[e];
#pragma unroll
        for (int j = 0; j < 12; ++j) acc += rl[j] * W_se[e * 12 + j];
        hrow(cl)[128 + e] = (_Float16)selu_(acc);
      }
    }
    __syncthreads();  // x visible for next step's afr
  }

  // ======== confidence head on hT (ah, hC hold final-step state) ========
  {
    f32x4 tac[8];
#pragma unroll
    for (int ct = 0; ct < 8; ++ct) {
      const _Float16* bp = cW1p + ct * 2048 + lane * 8;
      f32x4 a = {0.f, 0.f, 0.f, 0.f};
#pragma unroll
      for (int ch = 0; ch < 4; ++ch) {
        f16x8 b = *(const f16x8*)(bp + ch * 512);
        a = __builtin_amdgcn_mfma_f32_16x16x32_f16(ah[ch], b, a, 0, 0, 0);
      }
      tac[ct] = a;
    }
    f32x4 mean, rstd;
    {
      f32x4 s1 = {0.f, 0.f, 0.f, 0.f}, s2 = {0.f, 0.f, 0.f, 0.f};
#pragma unroll
      for (int ct = 0; ct < 8; ++ct) { s1 += tac[ct]; s2 += tac[ct] * tac[ct]; }
#pragma unroll
      for (int sh = 1; sh < 16; sh <<= 1) { s1 += shx4(s1, sh); s2 += shx4(s2, sh); }
      mean = s1 * (1.f / 128.f);
#pragma unroll
      for (int r = 0; r < 4; ++r)
        rstd[r] = rsqrtf(s2[r] * (1.f / 128.f) - mean[r] * mean[r] + 1e-5f);
    }
    __syncthreads();
#pragma unroll
    for (int ct = 0; ct < 8; ++ct) {
      const float g1 = cg1w[ct * 16 + cl];
      const float b1 = cg1b[ct * 16 + cl];
#pragma unroll
      for (int r = 0; r < 4; ++r) {
        float v = (tac[ct][r] - mean[r]) * rstd[r] * g1 + b1;
        t1row(q * 4 + r)[ct * 16 + cl] = (_Float16)fmaxf(v, 0.f);
      }
    }
    __syncthreads();
    f16x8 at1[4];
#pragma unroll
    for (int ch = 0; ch < 4; ++ch)
      at1[ch] = *(const f16x8*)(t1row(cl) + ch * 32 + q * 8);
    f32x4 t2a[8];
#pragma unroll
    for (int ct = 0; ct < 8; ++ct) {
      const _Float16* bp = cW2p + ct * 2048 + lane * 8;
      f32x4 a = {0.f, 0.f, 0.f, 0.f};
#pragma unroll
      for (int ch = 0; ch < 4; ++ch) {
        f16x8 b = *(const f16x8*)(bp + ch * 512);
        a = __builtin_amdgcn_mfma_f32_16x16x32_f16(at1[ch], b, a, 0, 0, 0);
      }
      t2a[ct] = a;
    }
    {
      f32x4 s1 = {0.f, 0.f, 0.f, 0.f}, s2 = {0.f, 0.f, 0.f, 0.f};
#pragma unroll
      for (int ct = 0; ct < 8; ++ct) { s1 += t2a[ct]; s2 += t2a[ct] * t2a[ct]; }
#pragma unroll
      for (int sh = 1; sh < 16; sh <<= 1) { s1 += shx4(s1, sh); s2 += shx4(s2, sh); }
      mean = s1 * (1.f / 128.f);
#pragma unroll
      for (int r = 0; r < 4; ++r)
        rstd[r] = rsqrtf(s2[r] * (1.f / 128.f) - mean[r] * mean[r] + 1e-5f);
    }
    float pl[4][6];
#pragma unroll
    for (int r = 0; r < 4; ++r)
#pragma unroll
      for (int k = 0; k < 6; ++k) pl[r][k] = 0.f;
#pragma unroll
    for (int ct = 0; ct < 8; ++ct) {
      const float g2 = cg2w[ct * 16 + cl];
      const float b2 = cg2b[ct * 16 + cl];
      float wo[6];
#pragma unroll
      for (int k = 0; k < 6; ++k) wo[k] = cWo[(ct * 16 + cl) * 6 + k];
#pragma unroll
      for (int r = 0; r < 4; ++r) {
        float v = (t2a[ct][r] - mean[r]) * rstd[r] * g2 + b2 + hC[ct][r];
        v = fmaxf(v, 0.f);
#pragma unroll
        for (int k = 0; k < 6; ++k) pl[r][k] += v * wo[k];
      }
    }
#pragma unroll
    for (int sh = 1; sh < 16; sh <<= 1)
#pragma unroll
      for (int r = 0; r < 4; ++r)
#pragma unroll
        for (int k = 0; k < 6; ++k) pl[r][k] += __shfl_xor(pl[r][k], sh, 64);
    if (cl == 0) {
#pragma unroll
      for (int r = 0; r < 4; ++r) {
        float l[6];
#pragma unroll
        for (int k = 0; k < 6; ++k) l[k] = pl[r][k] + cbo[k];
        float mx = l[0];
#pragma unroll
        for (int k = 1; k < 6; ++k) mx = fmaxf(mx, l[k]);
        float s = 0.f;
#pragma unroll
        for (int k = 0; k < 6; ++k) { l[k] = __expf(l[k] - mx); s += l[k]; }
        const float inv = fast_rcp(s);
#pragma unroll
        for (int k = 0; k < 6; ++k)
          out[confbase + (size_t)(rowbase + q * 4 + r) * 6 + k] = l[k] * inv;
      }
    }
  }
}

extern "C" void kernel_launch(void* const* d_in, const int* in_sizes, int n_in,
                              void* d_out, int out_size, void* d_ws, size_t ws_size,
                              hipStream_t stream) {
  (void)in_sizes; (void)n_in; (void)out_size; (void)ws_size;
  const float* last_obs_rel = (const float*)d_in[1];
  const float* h0   = (const float*)d_in[2];
  const float* c0   = (const float*)d_in[3];
  const float* W_se = (const float*)d_in[4];
  const float* b_se = (const float*)d_in[5];
  const float* W_ih = (const float*)d_in[6];
  const float* W_hh = (const float*)d_in[7];
  const float* b_ih = (const float*)d_in[8];
  const float* b_hh = (const float*)d_in[9];
  const float* mW1  = (const float*)d_in[10];
  const float* mg1w = (const float*)d_in[11];
  const float* mg1b = (const float*)d_in[12];
  const float* mW2  = (const float*)d_in[13];
  const float* mg2w = (const float*)d_in[14];
  const float* mg2b = (const float*)d_in[15];
  const float* mWo  = (const float*)d_in[16];
  const float* mbo  = (const float*)d_in[17];
  const float* cW1  = (const float*)d_in[18];
  const float* cg1w = (const float*)d_in[19];
  const float* cg1b = (const float*)d_in[20];
  const float* cW2  = (const float*)d_in[21];
  const float* cg2w = (const float*)d_in[22];
  const float* cg2b = (const float*)d_in[23];
  const float* cWo  = (const float*)d_in[24];
  const float* cbo  = (const float*)d_in[25];

  char* ws = (char*)d_ws;
  _Float16* Wg   = (_Float16*)(ws + 0);       // 512*160 f16   = 163840 B
  _Float16* W1p  = (_Float16*)(ws + 163840);  // 6*128*128 f16 = 196608 B
  _Float16* W2p  = (_Float16*)(ws + 360448);  // 6*128*128 f16 = 196608 B
  _Float16* cW1p = (_Float16*)(ws + 557056);  // 128*128 f16   =  32768 B
  _Float16* cW2p = (_Float16*)(ws + 589824);  // 128*128 f16   =  32768 B
  float*    bg   = (float*)   (ws + 622592);  // 512 f32       =   2048 B

  prep_weights<<<1218, 256, 0, stream>>>(W_ih, W_hh, b_ih, b_hh, mW1, mW2, cW1, cW2,
                                         Wg, W1p, W2p, cW1p, cW2p, bg);
  mmdec_main<<<B_ROWS / 64, 256, 0, stream>>>(last_obs_rel, h0, c0, W_se, b_se,
                                              mg1w, mg1b, mg2w, mg2b, mWo, mbo,
                                              cg1w, cg1b, cg2w, cg2b, cWo, cbo,
                                              Wg, W1p, W2p, cW1p, cW2p, bg, (float*)d_out);
}